// Round 19
// baseline (55.176 us; speedup 1.0000x reference)
//
#include <hip/hip_runtime.h>
#include <hip/hip_bf16.h>
#include <math.h>

#define NROW 256
#define DIM  65536
#define LSTR 264            // LDS staging row stride in ushorts (256 + 8 pad)
#define SB   264            // byte stride of the fp8 transpose view
#define PSPB 65600          // partial stride in BYTES (65536 + 64 pad)

typedef __attribute__((ext_vector_type(8))) short short8;
typedef __attribute__((ext_vector_type(4))) float f32x4;
typedef __attribute__((ext_vector_type(4))) float ef4;        // nt-compatible
typedef __attribute__((ext_vector_type(2))) unsigned int eu2; // nt-compatible
typedef unsigned int       u32t;
typedef unsigned char      u8t;
typedef unsigned long long u64t;

__device__ __forceinline__ float bf2f(ushort h) {
    u32t u = ((u32t)h) << 16;
    return __builtin_bit_cast(float, u);
}
// packed fp32x2 -> bf16x2 (v_cvt_pk_bf16_f32, RNE)
__device__ __forceinline__ u32t pk2(float lo, float hi) {
    __hip_bfloat162 h = __float22bfloat162_rn(make_float2(lo, hi));
    u32t r; __builtin_memcpy(&r, &h, 4); return r;
}
// manual fp32 -> fp8 e4m3fn (RNE, saturating) - no API/builtin risk
__device__ __forceinline__ u32t f2fp8(float f) {
    const u32t u  = __builtin_bit_cast(u32t, f);
    const u32t sg = (u >> 31) << 7;
    const u32t au = u & 0x7fffffffu;
    u32t r;
    if (au >= 0x43e80000u) {                 // >= 464 -> saturate to 448
        r = 0x7eu;
    } else if (au < 0x3c800000u) {           // < 2^-6: subnormal octave
        const float af = __builtin_bit_cast(float, au);
        r = (u32t)(int)rintf(af * 512.0f);   // 0..8 (8 == min normal, exact)
    } else {                                 // normal, RNE at bit 20
        const u32t m = au + 0x7ffffu + ((au >> 20) & 1u);
        r = ((m >> 20) - (120u << 3)) & 0x7fu;
    }
    return r | sg;
}
// manual fp8 e4m3fn -> fp32
__device__ __forceinline__ float fp82f(u32t h) {
    const u32t e    = (h >> 3) & 0xfu;
    const u32t mant = h & 7u;
    const u32t sg   = (h >> 7) << 31;
    const float nrm = __builtin_bit_cast(float, ((e + 120u) << 23) | (mant << 20));
    const float sub = (float)(int)mant * 0.001953125f;   // m * 2^-9
    const float mag = e ? nrm : sub;
    return __builtin_bit_cast(float, __builtin_bit_cast(u32t, mag) | sg);
}

// ---------------------------------------------------------------------------
// Split-K MFMA GEMM = round 14 structure, partials narrowed to fp8 e4m3.
//  Stage:  wave w rows [w*32,+32); 1 instr = 64 lanes x 16 B = 1 KB
//          contiguous per row (nt - read once). cvt_pk -> ds_write_b64.
//  MFMA:   8 k-steps, 8 waves x (128x64), acc[8][4].
//  Diag:   captured from fp32 acc PRE-quantization -> fixed-point i64
//          atomics (order-independent => deterministic); fp8 diag unused.
//  Epilogue: acc -> fp8 -> LDS transpose (byte view) -> coalesced nt u32
//          column stores (same instr count as r14, half the bytes).
//          G symmetric => storing G^T in plain [i][j] IS G.
// ---------------------------------------------------------------------------
__global__ __launch_bounds__(512) void gemm_k(const float* __restrict__ E,
                                              u8t* __restrict__ part,
                                              u64t* __restrict__ sqacc) {
    const int s    = blockIdx.x;
    const int tid  = threadIdx.x;
    const int lane = tid & 63;
    const int wid  = tid >> 6;
    const int wr   = wid >> 2;          // 0..1 -> 128-row band
    const int wc   = wid & 3;           // 0..3 -> 64-col band
    const int r15  = lane & 15;
    const int kgi  = lane >> 4;         // 0..3 -> 8-k slice within k=32

    __shared__ ushort es[NROW][LSTR];   // 135 KB; staging, then transpose buf

    // ---------------- stage: coalesced 1 KB row reads (nt) ----------------
    {
        const int wrow = wid * 32;
        ef4 v[32];
        #pragma unroll
        for (int i = 0; i < 32; ++i) {
            const int row = wrow + i;
            v[i] = __builtin_nontemporal_load(
                (const ef4*)(E + ((size_t)row << 16)
                               + (size_t)s * 256 + lane * 4));
        }
        #pragma unroll
        for (int i = 0; i < 32; ++i) {
            const int row = wrow + i;
            eu2 wv;
            wv.x = pk2(v[i].x, v[i].y);
            wv.y = pk2(v[i].z, v[i].w);
            *(eu2*)&es[row][lane * 4] = wv;
        }
    }
    __syncthreads();

    // ---------------- MFMA: 8 k-steps of K=32 ----------------
    f32x4 acc[8][4];
    #pragma unroll
    for (int m = 0; m < 8; ++m)
        #pragma unroll
        for (int n = 0; n < 4; ++n) acc[m][n] = (f32x4){0.f, 0.f, 0.f, 0.f};

    #pragma unroll
    for (int kk = 0; kk < 8; ++kk) {
        const int ko = kk * 32 + kgi * 8;
        short8 af[8], bfr[4];
        #pragma unroll
        for (int m = 0; m < 8; ++m)
            af[m] = *(const short8*)&es[wr * 128 + m * 16 + r15][ko];
        #pragma unroll
        for (int n = 0; n < 4; ++n)
            bfr[n] = *(const short8*)&es[wc * 64 + n * 16 + r15][ko];
        #pragma unroll
        for (int m = 0; m < 8; ++m)
            #pragma unroll
            for (int n = 0; n < 4; ++n)
                acc[m][n] = __builtin_amdgcn_mfma_f32_16x16x32_bf16(
                    af[m], bfr[n], acc[m][n], 0, 0, 0);
    }

    __syncthreads();    // all frag reads done; es reusable as fp8 [col][row]

    const int rq = (lane >> 4) * 4;     // row-quad base within 16-row block

    // diagonal capture (exact fp32, pre-quantization) -> i64 fixed point
    #pragma unroll
    for (int m = 0; m < 8; ++m)
        #pragma unroll
        for (int n = 0; n < 4; ++n) {
            const int col  = wc * 64 + n * 16 + r15;
            const int rowb = wr * 128 + m * 16 + rq;
            const u32t e = (u32t)(col - rowb);
            if (e < 4u) {
                const float dv = (e == 0) ? acc[m][n][0]
                               : (e == 1) ? acc[m][n][1]
                               : (e == 2) ? acc[m][n][2] : acc[m][n][3];
                atomicAdd(sqacc + col,
                          (u64t)(long long)llrintf(dv * 1048576.0f));
            }
        }

    // ---------------- epilogue: fp8 LDS transpose ----------------
    u8t* esb = (u8t*)&es[0][0];
    #pragma unroll
    for (int m = 0; m < 8; ++m)
        #pragma unroll
        for (int n = 0; n < 4; ++n) {
            const int col  = wc * 64 + n * 16 + r15;
            const int rowb = wr * 128 + m * 16 + rq;
            const u32t q = f2fp8(acc[m][n][0])
                         | (f2fp8(acc[m][n][1]) << 8)
                         | (f2fp8(acc[m][n][2]) << 16)
                         | (f2fp8(acc[m][n][3]) << 24);
            *(u32t*)(esb + col * SB + rowb) = q;   // es viewed as [col][row]
        }
    __syncthreads();

    // coalesced nt store-out: wave w streams cols [w*32, +32), 256 B/column
    u8t* pb = part + (size_t)s * PSPB;
    #pragma unroll
    for (int i = 0; i < 32; ++i) {
        const int col = wid * 32 + i;
        const u32t q = *(const u32t*)(esb + col * SB + lane * 4);
        __builtin_nontemporal_store(q, (u32t*)(pb + col * 256 + lane * 4));
    }
}

// ---------------------------------------------------------------------------
// Reduce 256 fp8 partials -> Gn (fp32, plain [i*256+j]). 4 s-groups of 64
// (fixed assignment); lane loads u32 = 4 positions, 16-deep batches, s
// ascending within group; fixed pairwise tree across groups. Deterministic.
// Also zeroes the fixed-point accumulator for row_loss (stream-ordered).
// ---------------------------------------------------------------------------
__global__ __launch_bounds__(256) void reduce_k(const u8t* __restrict__ part,
                                                float* __restrict__ Gn,
                                                u64t* __restrict__ acc,
                                                u32t* __restrict__ cnt) {
    if (blockIdx.x == 0 && threadIdx.x == 0) { *acc = 0ull; *cnt = 0u; }

    const int b  = blockIdx.x;          // 256-position window
    const int t  = threadIdx.x;
    const int l  = t & 63, sg = t >> 6; // 4 partial-groups of 64
    const u8t* base = part + (size_t)b * 256 + (size_t)l * 4;

    float f0 = 0.f, f1 = 0.f, f2 = 0.f, f3 = 0.f;
    for (int g = 0; g < 4; ++g) {
        u32t v[16];
        #pragma unroll
        for (int u = 0; u < 16; ++u)
            v[u] = __builtin_nontemporal_load(
                (const u32t*)(base + (size_t)(sg * 64 + g * 16 + u) * PSPB));
        #pragma unroll
        for (int u = 0; u < 16; ++u) {
            f0 += fp82f(v[u] & 0xffu);
            f1 += fp82f((v[u] >> 8) & 0xffu);
            f2 += fp82f((v[u] >> 16) & 0xffu);
            f3 += fp82f(v[u] >> 24);
        }
    }
    __shared__ float sh[4][256];
    sh[sg][l * 4 + 0] = f0; sh[sg][l * 4 + 1] = f1;
    sh[sg][l * 4 + 2] = f2; sh[sg][l * 4 + 3] = f3;
    __syncthreads();
    Gn[b * 256 + t] = (sh[0][t] + sh[1][t]) + (sh[2][t] + sh[3][t]);
}

// ---------------------------------------------------------------------------
// Fused per-row softmax loss + deterministic final sum. Diagonal (sq) from
// the exact fixed-point accumulator, NOT the fp8 Gn diag. PSD term provably
// 0 (AM-GM; clip at 0), omitted.
// ---------------------------------------------------------------------------
__global__ __launch_bounds__(256) void row_loss_k(const float* __restrict__ Gn,
                                                  const u64t* __restrict__ sqacc,
                                                  const int* __restrict__ labels,
                                                  u64t* __restrict__ acc,
                                                  u32t* __restrict__ cnt,
                                                  float* __restrict__ out) {
    const int i = blockIdx.x;
    const int j = threadIdx.x;

    const float Gii = (float)((double)(long long)sqacc[i] * (1.0 / 1048576.0));
    const float Gjj = (float)((double)(long long)sqacc[j] * (1.0 / 1048576.0));
    const float Gij = Gn[i * 256 + j];
    const float d2 = fmaxf(Gii + Gjj - 2.0f * Gij, 0.0f);
    const bool diag = (j == i);
    const float sc = diag ? -3.0e38f : -sqrtf(d2);

    __shared__ float red0[4], red1[4];

    float m = sc;
    #pragma unroll
    for (int off = 32; off; off >>= 1) m = fmaxf(m, __shfl_xor(m, off, 64));
    const int w = j >> 6;
    if ((j & 63) == 0) red0[w] = m;
    __syncthreads();
    m = fmaxf(fmaxf(red0[0], red0[1]), fmaxf(red0[2], red0[3]));

    const float p  = diag ? 0.0f : expf(sc - m);
    const float nm = (labels[j] == labels[i]) ? p : 0.0f;

    float zs = p, ns = nm;
    #pragma unroll
    for (int off = 32; off; off >>= 1) {
        zs += __shfl_xor(zs, off, 64);
        ns += __shfl_xor(ns, off, 64);
    }
    __syncthreads();
    if ((j & 63) == 0) { red0[w] = zs; red1[w] = ns; }
    __syncthreads();
    if (j == 0) {
        const float Z = red0[0] + red0[1] + red0[2] + red0[3];
        const float N = red1[0] + red1[1] + red1[2] + red1[3];
        const float rl = logf(Z) - logf(N);          // >= 0 (N subset of Z)
        const long long q = llrintf(rl * 1048576.0f);
        atomicAdd(acc, (u64t)q);
        __threadfence();
        const u32t c = atomicAdd(cnt, 1u);
        if (c == NROW - 1) {
            __threadfence();
            const u64t tot = atomicAdd(acc, 0ull);
            out[0] = (float)((double)(long long)tot * (1.0 / 1048576.0) * 0.005);
        }
    }
}

extern "C" void kernel_launch(void* const* d_in, const int* in_sizes, int n_in,
                              void* d_out, int out_size, void* d_ws, size_t ws_size,
                              hipStream_t stream) {
    const float* E      = (const float*)d_in[0];
    const int*   labels = (const int*)d_in[1];
    float*       out    = (float*)d_out;

    u8t*   part  = (u8t*)d_ws;                            // 256 * PSPB bytes
    float* Gn    = (float*)((u8t*)d_ws + (size_t)256 * PSPB);
    u64t*  sqacc = (u64t*)(Gn + 65536);
    u64t*  acc   = sqacc + 256;
    u32t*  cnt   = (u32t*)(acc + 1);

    hipMemsetAsync((void*)sqacc, 0, 256 * sizeof(u64t), stream);

    gemm_k    <<<256, 512, 0, stream>>>(E, part, sqacc);
    reduce_k  <<<256, 256, 0, stream>>>(part, Gn, acc, cnt);
    row_loss_k<<<NROW, 256, 0, stream>>>(Gn, sqacc, labels, acc, cnt, out);
}

// Round 20
// 43.426 us; speedup vs baseline: 1.2706x; 1.2706x over previous
//
#include <hip/hip_runtime.h>
#include <hip/hip_bf16.h>
#include <math.h>

#define NROW 256
#define DIM  65536
#define LSTR 264            // LDS row stride in ushorts (256 + 8 pad)
#define PSP  65600          // partial stride in ushorts (65536 + 64 pad)

typedef __attribute__((ext_vector_type(8))) short short8;
typedef __attribute__((ext_vector_type(4))) float f32x4;
typedef __attribute__((ext_vector_type(4))) float ef4;       // nt-compatible
typedef __attribute__((ext_vector_type(2))) unsigned int eu2; // nt-compatible
typedef unsigned int       u32t;
typedef unsigned long long u64t;

__device__ __forceinline__ float bf2f(ushort h) {
    u32t u = ((u32t)h) << 16;
    return __builtin_bit_cast(float, u);
}
// packed fp32x2 -> bf16x2 (v_cvt_pk_bf16_f32, RNE)
__device__ __forceinline__ u32t pk2(float lo, float hi) {
    __hip_bfloat162 h = __float22bfloat162_rn(make_float2(lo, hi));
    u32t r; __builtin_memcpy(&r, &h, 4); return r;
}

// ---------------------------------------------------------------------------
// Split-K MFMA GEMM, fully-coalesced (empirical best, = rounds 14/18).
//  Stage:  wave w rows [w*32,+32); 1 instr = 64 lanes x 16 B = 1 KB
//          contiguous per row (nt - read once). cvt_pk -> ds_write_b64.
//  MFMA:   8 k-steps, 8 waves x (128x64), acc[8][4].
//  Epilogue: acc -> LDS transpose -> coalesced nt stores of whole columns.
//          G symmetric => storing G^T in plain [i][j] IS G.
// ---------------------------------------------------------------------------
__global__ __launch_bounds__(512) void gemm_k(const float* __restrict__ E,
                                              ushort* __restrict__ part) {
    const int s    = blockIdx.x;
    const int tid  = threadIdx.x;
    const int lane = tid & 63;
    const int wid  = tid >> 6;
    const int wr   = wid >> 2;          // 0..1 -> 128-row band
    const int wc   = wid & 3;           // 0..3 -> 64-col band
    const int r15  = lane & 15;
    const int kgi  = lane >> 4;         // 0..3 -> 8-k slice within k=32

    __shared__ ushort es[NROW][LSTR];   // 135 KB; staging, then transpose buf

    // ---------------- stage: coalesced 1 KB row reads (nt) ----------------
    {
        const int wrow = wid * 32;
        ef4 v[32];
        #pragma unroll
        for (int i = 0; i < 32; ++i) {
            const int row = wrow + i;
            v[i] = __builtin_nontemporal_load(
                (const ef4*)(E + ((size_t)row << 16)
                               + (size_t)s * 256 + lane * 4));
        }
        #pragma unroll
        for (int i = 0; i < 32; ++i) {
            const int row = wrow + i;
            eu2 wv;
            wv.x = pk2(v[i].x, v[i].y);
            wv.y = pk2(v[i].z, v[i].w);
            *(eu2*)&es[row][lane * 4] = wv;
        }
    }
    __syncthreads();

    // ---------------- MFMA: 8 k-steps of K=32 ----------------
    f32x4 acc[8][4];
    #pragma unroll
    for (int m = 0; m < 8; ++m)
        #pragma unroll
        for (int n = 0; n < 4; ++n) acc[m][n] = (f32x4){0.f, 0.f, 0.f, 0.f};

    #pragma unroll
    for (int kk = 0; kk < 8; ++kk) {
        const int ko = kk * 32 + kgi * 8;
        short8 af[8], bfr[4];
        #pragma unroll
        for (int m = 0; m < 8; ++m)
            af[m] = *(const short8*)&es[wr * 128 + m * 16 + r15][ko];
        #pragma unroll
        for (int n = 0; n < 4; ++n)
            bfr[n] = *(const short8*)&es[wc * 64 + n * 16 + r15][ko];
        #pragma unroll
        for (int m = 0; m < 8; ++m)
            #pragma unroll
            for (int n = 0; n < 4; ++n)
                acc[m][n] = __builtin_amdgcn_mfma_f32_16x16x32_bf16(
                    af[m], bfr[n], acc[m][n], 0, 0, 0);
    }

    __syncthreads();    // all frag reads done; es reusable as [col][row]

    // ---------------- epilogue: LDS transpose ----------------
    const int rq = (lane >> 4) * 4;     // row-quad base within 16-row block
    #pragma unroll
    for (int m = 0; m < 8; ++m)
        #pragma unroll
        for (int n = 0; n < 4; ++n) {
            const int col  = wc * 64 + n * 16 + r15;
            const int rowb = wr * 128 + m * 16 + rq;
            eu2 wv;
            wv.x = pk2(acc[m][n][0], acc[m][n][1]);
            wv.y = pk2(acc[m][n][2], acc[m][n][3]);
            *(eu2*)&es[col][rowb] = wv;   // es viewed as [col][row]
        }
    __syncthreads();

    // coalesced nt store-out: wave w streams cols [w*32, w*32+32)
    ushort* pb = part + (size_t)s * PSP;
    #pragma unroll
    for (int i = 0; i < 32; ++i) {
        const int col = wid * 32 + i;
        const eu2 q = *(const eu2*)&es[col][lane * 4];
        __builtin_nontemporal_store(q, (eu2*)(pb + col * 256 + lane * 4));
    }
}

// ---------------------------------------------------------------------------
// Reduce 256 bf16 partials -> Gn (fp32, PLAIN [i*256+j] layout), nt reads.
// One position per thread; 8 fixed-order groups of 32 (deterministic tree).
// Also zeroes the fixed-point accumulator for row_loss (stream-ordered).
// ---------------------------------------------------------------------------
__global__ __launch_bounds__(256) void reduce_k(const ushort* __restrict__ part,
                                                float* __restrict__ Gn,
                                                u64t* __restrict__ acc,
                                                u32t* __restrict__ cnt) {
    if (blockIdx.x == 0 && threadIdx.x == 0) { *acc = 0ull; *cnt = 0u; }

    const int pos = blockIdx.x * 256 + threadIdx.x;   // 0..65535
    const ushort* base = part + pos;

    float g[8];
    #pragma unroll
    for (int q = 0; q < 8; ++q) {
        float a = 0.f;
        #pragma unroll
        for (int u = 0; u < 32; ++u)
            a += bf2f(__builtin_nontemporal_load(
                          base + (size_t)(q * 32 + u) * PSP));
        g[q] = a;
    }
    Gn[pos] = ((g[0] + g[1]) + (g[2] + g[3])) + ((g[4] + g[5]) + (g[6] + g[7]));
}

// ---------------------------------------------------------------------------
// Fused per-row softmax loss + deterministic final sum (fixed-point atomic,
// order-independent). PSD term provably 0 (AM-GM; clip at 0), omitted.
// ---------------------------------------------------------------------------
__global__ __launch_bounds__(256) void row_loss_k(const float* __restrict__ Gn,
                                                  const int* __restrict__ labels,
                                                  u64t* __restrict__ acc,
                                                  u32t* __restrict__ cnt,
                                                  float* __restrict__ out) {
    const int i = blockIdx.x;
    const int j = threadIdx.x;

    const float Gii = Gn[i * 256 + i];
    const float Gjj = Gn[j * 256 + j];
    const float Gij = Gn[i * 256 + j];
    const float d2 = fmaxf(Gii + Gjj - 2.0f * Gij, 0.0f);
    const bool diag = (j == i);
    const float sc = diag ? -3.0e38f : -sqrtf(d2);

    __shared__ float red0[4], red1[4];

    float m = sc;
    #pragma unroll
    for (int off = 32; off; off >>= 1) m = fmaxf(m, __shfl_xor(m, off, 64));
    const int w = j >> 6;
    if ((j & 63) == 0) red0[w] = m;
    __syncthreads();
    m = fmaxf(fmaxf(red0[0], red0[1]), fmaxf(red0[2], red0[3]));

    const float p  = diag ? 0.0f : expf(sc - m);
    const float nm = (labels[j] == labels[i]) ? p : 0.0f;

    float zs = p, ns = nm;
    #pragma unroll
    for (int off = 32; off; off >>= 1) {
        zs += __shfl_xor(zs, off, 64);
        ns += __shfl_xor(ns, off, 64);
    }
    __syncthreads();
    if ((j & 63) == 0) { red0[w] = zs; red1[w] = ns; }
    __syncthreads();
    if (j == 0) {
        const float Z = red0[0] + red0[1] + red0[2] + red0[3];
        const float N = red1[0] + red1[1] + red1[2] + red1[3];
        const float rl = logf(Z) - logf(N);          // >= 0 (N subset of Z)
        const long long q = llrintf(rl * 1048576.0f);
        atomicAdd(acc, (u64t)q);
        __threadfence();
        const u32t c = atomicAdd(cnt, 1u);
        if (c == NROW - 1) {
            __threadfence();
            const u64t tot = atomicAdd(acc, 0ull);
            out[0] = (float)((double)(long long)tot * (1.0 / 1048576.0) * 0.005);
        }
    }
}

extern "C" void kernel_launch(void* const* d_in, const int* in_sizes, int n_in,
                              void* d_out, int out_size, void* d_ws, size_t ws_size,
                              hipStream_t stream) {
    const float* E      = (const float*)d_in[0];
    const int*   labels = (const int*)d_in[1];
    float*       out    = (float*)d_out;

    ushort* part = (ushort*)d_ws;                         // 256 * PSP ushorts
    float*  Gn   = (float*)((char*)d_ws + (size_t)256 * PSP * sizeof(ushort));
    u64t*   acc  = (u64t*)(Gn + 65536);
    u32t*   cnt  = (u32t*)(acc + 1);

    gemm_k    <<<256, 512, 0, stream>>>(E, part);
    reduce_k  <<<256, 256, 0, stream>>>(part, Gn, acc, cnt);
    row_loss_k<<<NROW, 256, 0, stream>>>(Gn, labels, acc, cnt, out);
}